// Round 11
// baseline (161.302 us; speedup 1.0000x reference)
//
#include <hip/hip_runtime.h>
#include <hip/hip_bf16.h>
#include <math.h>

#define STU_NUM   100000
#define PROB_NUM  20000
#define KNOW_NUM  128
#define DIM       128
#define BATCH     8192
#define HIDDEN    512

typedef __attribute__((ext_vector_type(4))) float  f32x4;
typedef __attribute__((ext_vector_type(8))) __bf16 bf16x8;

__device__ __forceinline__ float sigmoidf_(float x) { return 1.0f / (1.0f + __expf(-x)); }
__device__ __forceinline__ float tanh_fast(float x) { return 1.0f - 2.0f / (__expf(2.0f * x) + 1.0f); }

__device__ __forceinline__ int swz(int row, int kk) {
    return row * 128 + ((((kk >> 3) ^ (row & 7)) << 4) | ((kk & 7) << 1));
}
__device__ __forceinline__ bf16x8 rfragK(const char* buf, int row, int kk) {
    return *reinterpret_cast<const bf16x8*>(buf + (kk >> 6) * 4096 + swz(row, kk & 63));
}
__device__ __forceinline__ void wput(char* buf, int row, int col, float v) {
    *reinterpret_cast<__bf16*>(buf + (col >> 6) * 4096 + swz(row, col & 63)) = (__bf16)v;
}
__device__ __forceinline__ f32x4 mfma16(bf16x8 a, bf16x8 b, f32x4 c) {
    return __builtin_amdgcn_mfma_f32_16x16x32_bf16(a, b, c, 0, 0, 0);
}

// ---------------------------------------------------------------------------
// MLP layer with FORCED breadth-first weight preload.
// R10 lesson: without a scheduling fence the compiler sinks the preload back
// to the uses (probe_w2R: VGPR=60, 8.27us/rep unchanged). sched_barrier(0)
// pins every weight load BEFORE the first MFMA -- regalloc must keep all
// NKT*CG frags live (W2: 128 VGPR), and the loads drain pipelined behind a
// single L2-latency exposure instead of NKT serial ones.
// ---------------------------------------------------------------------------
template<int N, int K>
__device__ __forceinline__ void layerF(const __bf16* __restrict__ WT,
                                       const float* __restrict__ bias,
                                       const char* __restrict__ A, char* __restrict__ O,
                                       int wid, int lane) {
    constexpr int NKT = K / 32;
    constexpr int CG  = N / 128;
    const int l15 = lane & 15, lk = (lane >> 4) * 8;
    const int nb = wid * (N / 8);

    bf16x8 wf[NKT][CG];
    #pragma unroll
    for (int kt = 0; kt < NKT; ++kt)
        #pragma unroll
        for (int c = 0; c < CG; ++c)
            wf[kt][c] = *reinterpret_cast<const bf16x8*>(
                WT + (size_t)(nb + c * 16 + l15) * K + kt * 32 + lk);
    __builtin_amdgcn_sched_barrier(0);   // no MFMA above, no load below

    f32x4 acc[2][CG];
    #pragma unroll
    for (int i = 0; i < 2; ++i)
        #pragma unroll
        for (int c = 0; c < CG; ++c) acc[i][c] = (f32x4){0.f, 0.f, 0.f, 0.f};

    #pragma unroll
    for (int kt = 0; kt < NKT; ++kt) {
        const int kk = kt * 32 + lk;
        bf16x8 a0 = rfragK(A, l15, kk);
        bf16x8 a1 = rfragK(A, 16 + l15, kk);
        #pragma unroll
        for (int c = 0; c < CG; ++c) {
            acc[0][c] = mfma16(a0, wf[kt][c], acc[0][c]);
            acc[1][c] = mfma16(a1, wf[kt][c], acc[1][c]);
        }
    }
    #pragma unroll
    for (int c = 0; c < CG; ++c) {
        const int col = nb + c * 16 + l15;
        const float bv = bias[col];
        #pragma unroll
        for (int i = 0; i < 2; ++i)
            #pragma unroll
            for (int r = 0; r < 4; ++r)
                wput(O, i * 16 + (lane >> 4) * 4 + r, col, tanh_fast(acc[i][c][r] + bv));
    }
}

// ---------------------------------------------------------------------------
// Fused kernel: R4 structure + 256-VGPR budget + FORCED breadth preload.
// ---------------------------------------------------------------------------
__global__ __launch_bounds__(512, 2) void fused_kernel(
    const float* __restrict__ z, const int* __restrict__ sid, const int* __restrict__ eid,
    const float* __restrict__ kp, const float* __restrict__ bstat, const float* __restrict__ bkdiff,
    const float* __restrict__ w_stat, const float* __restrict__ w_kdiff,
    const __bf16* __restrict__ KB, const __bf16* __restrict__ W1T,
    const __bf16* __restrict__ W2T, const __bf16* __restrict__ W3T,
    const float* __restrict__ b1, const float* __restrict__ b2, const float* __restrict__ b3,
    const float* __restrict__ W4, const float* __restrict__ b4,
    float* __restrict__ out) {
    __shared__ char lds[81920];
    char* Xs = lds;
    char* Xk = lds + 8192;
    char* st = lds + 16384;
    char* h1 = lds + 24576;
    char* h2 = lds + 57344;
    char* h3 = lds + 73728;

    const int t = threadIdx.x, lane = t & 63, wid = t >> 6;
    const int l15 = lane & 15, lk = (lane >> 4) * 8;
    const int rb0 = blockIdx.x * 32;
    const int colb = wid * 16 + l15;

    {
        int gr = t >> 3, row = gr & 31;
        bool ise = gr >= 32;
        int zrow = ise ? eid[rb0 + row] : sid[rb0 + row];
        const float* w = ise ? w_kdiff : w_stat;
        char* Xb = ise ? Xk : Xs;
        int c0 = (t & 7) * 16;
        const float4* zp = reinterpret_cast<const float4*>(z + (size_t)zrow * DIM + c0);
        const float4* wp = reinterpret_cast<const float4*>(w + c0);
        #pragma unroll
        for (int q = 0; q < 2; ++q) {
            float4 za = zp[2 * q], zb = zp[2 * q + 1];
            float4 wa = wp[2 * q], wb = wp[2 * q + 1];
            bf16x8 o;
            o[0] = (__bf16)(za.x * wa.x);  o[1] = (__bf16)(za.y * wa.y);
            o[2] = (__bf16)(za.z * wa.z);  o[3] = (__bf16)(za.w * wa.w);
            o[4] = (__bf16)(zb.x * wb.x);  o[5] = (__bf16)(zb.y * wb.y);
            o[6] = (__bf16)(zb.z * wb.z);  o[7] = (__bf16)(zb.w * wb.w);
            int c = c0 + q * 8;
            *reinterpret_cast<bf16x8*>(Xb + (c >> 6) * 4096 + swz(row, c & 63)) = o;
        }
    }
    bf16x8 kbf[4];
    #pragma unroll
    for (int kt = 0; kt < 4; ++kt)
        kbf[kt] = *reinterpret_cast<const bf16x8*>(KB + (size_t)colb * DIM + kt * 32 + lk);
    float kpv[2][4];
    #pragma unroll
    for (int i = 0; i < 2; ++i)
        #pragma unroll
        for (int r = 0; r < 4; ++r)
            kpv[i][r] = kp[(size_t)(rb0 + i * 16 + (lane >> 4) * 4 + r) * KNOW_NUM + colb];
    __syncthreads();

    {
        f32x4 aS[2], aK[2];
        #pragma unroll
        for (int i = 0; i < 2; ++i) { aS[i] = (f32x4){0,0,0,0}; aK[i] = (f32x4){0,0,0,0}; }
        #pragma unroll
        for (int kt = 0; kt < 4; ++kt) {
            const int kk = kt * 32 + lk;
            bf16x8 s0 = rfragK(Xs, l15, kk), s1 = rfragK(Xs, 16 + l15, kk);
            bf16x8 q0 = rfragK(Xk, l15, kk), q1 = rfragK(Xk, 16 + l15, kk);
            aS[0] = mfma16(s0, kbf[kt], aS[0]);
            aS[1] = mfma16(s1, kbf[kt], aS[1]);
            aK[0] = mfma16(q0, kbf[kt], aK[0]);
            aK[1] = mfma16(q1, kbf[kt], aK[1]);
        }
        const float bs = bstat[0], bk = bkdiff[0];
        #pragma unroll
        for (int i = 0; i < 2; ++i)
            #pragma unroll
            for (int r = 0; r < 4; ++r) {
                float v = kpv[i][r] * (sigmoidf_(aS[i][r] + bs) - sigmoidf_(aK[i][r] + bk));
                wput(st, i * 16 + (lane >> 4) * 4 + r, colb, v);
            }
    }
    __syncthreads();

    layerF<HIDDEN,     DIM>       (W1T, b1, st, h1, wid, lane);
    __syncthreads();
    layerF<HIDDEN / 2, HIDDEN>    (W2T, b2, h1, h2, wid, lane);
    __syncthreads();
    layerF<HIDDEN / 4, HIDDEN / 2>(W3T, b3, h2, h3, wid, lane);
    __syncthreads();

    {
        int row  = t >> 4;
        int part = (t & 15) * 8;
        bf16x8 h = rfragK(h3, row, part);
        float s = 0.f;
        #pragma unroll
        for (int j = 0; j < 8; ++j) s += (float)h[j] * W4[part + j];
        s += __shfl_xor(s, 1); s += __shfl_xor(s, 2);
        s += __shfl_xor(s, 4); s += __shfl_xor(s, 8);
        if ((t & 15) == 0) out[rb0 + row] = sigmoidf_(s + b4[0]);
    }
}

// ---------------------------------------------------------------------------
// probe_w2F: verifies the FORCED preload. Expect VGPR >= 160 (was 60) and
// per-rep <= 2.5us (was 8.27). If VGPR still ~60 -> sched_barrier defeated,
// next round uses raw inline-asm global_load_dwordx4.
// ---------------------------------------------------------------------------
__global__ __launch_bounds__(512, 2) void probe_w2F(
    const __bf16* __restrict__ WT, const float* __restrict__ bias,
    float* __restrict__ sink, int reps) {
    __shared__ char lds[81920];
    const int t = threadIdx.x, lane = t & 63, wid = t >> 6;
    for (int i = t; i < 20480; i += 512) reinterpret_cast<unsigned*>(lds)[i] = 0x3DCC3DCCu;
    __syncthreads();
    #pragma unroll 1
    for (int rep = 0; rep < reps; ++rep) {
        int off = 0; asm volatile("" : "+s"(off));
        layerF<HIDDEN / 2, HIDDEN>(WT + off, bias, (const char*)lds + off, lds + 40960, wid, lane);
        __syncthreads();
    }
    if (t == 0) sink[blockIdx.x] = *reinterpret_cast<float*>(lds + 40960);
}

// ---------------------------------------------------------------------------
// prep: f32 -> bf16 weight reorg, READ-coalesced (unchanged).
// ---------------------------------------------------------------------------
__global__ void prep_kernel(const float* __restrict__ z,
                            const float* __restrict__ W1, const float* __restrict__ W2,
                            const float* __restrict__ W3,
                            __bf16* __restrict__ KB, __bf16* __restrict__ W1T,
                            __bf16* __restrict__ W2T, __bf16* __restrict__ W3T) {
    int i = blockIdx.x * 256 + threadIdx.x;
    if (i < 16384) { KB[i] = (__bf16)z[(size_t)(STU_NUM + PROB_NUM) * DIM + i]; return; }
    i -= 16384;
    if (i < 65536) {
        int k = i >> 9, n = i & 511;
        W1T[(size_t)n * DIM + k] = (__bf16)W1[i]; return;
    }
    i -= 65536;
    if (i < 131072) {
        int k = i >> 8, n = i & 255;
        W2T[(size_t)n * HIDDEN + k] = (__bf16)W2[i]; return;
    }
    i -= 131072;
    if (i < 32768) {
        int k = i >> 7, n = i & 127;
        W3T[(size_t)n * (HIDDEN / 2) + k] = (__bf16)W3[i];
    }
}

extern "C" void kernel_launch(void* const* d_in, const int* in_sizes, int n_in,
                              void* d_out, int out_size, void* d_ws, size_t ws_size,
                              hipStream_t stream) {
    const float* z       = (const float*)d_in[0];
    const int*   sid     = (const int*)d_in[1];
    const int*   eid     = (const int*)d_in[2];
    const float* kp      = (const float*)d_in[3];
    const float* w_stat  = (const float*)d_in[4];
    const float* b_stat  = (const float*)d_in[5];
    const float* w_kdiff = (const float*)d_in[6];
    const float* b_kdiff = (const float*)d_in[7];
    const float* W1      = (const float*)d_in[8];
    const float* b1      = (const float*)d_in[9];
    const float* W2      = (const float*)d_in[10];
    const float* b2      = (const float*)d_in[11];
    const float* W3      = (const float*)d_in[12];
    const float* b3      = (const float*)d_in[13];
    const float* W4      = (const float*)d_in[14];
    const float* b4      = (const float*)d_in[15];
    float* out = (float*)d_out;

    char* ws = (char*)d_ws;
    __bf16* KB  = (__bf16*)(ws + 0);        //  32 KB
    __bf16* W1T = (__bf16*)(ws + 32768);    // 128 KB
    __bf16* W2T = (__bf16*)(ws + 163840);   // 256 KB
    __bf16* W3T = (__bf16*)(ws + 425984);   //  64 KB
    float* sinkW2 = (float*)(ws + (1 << 20));

    hipLaunchKernelGGL(prep_kernel, dim3(960), dim3(256), 0, stream,
                       z, W1, W2, W3, KB, W1T, W2T, W3T);

    hipLaunchKernelGGL(fused_kernel, dim3(BATCH / 32), dim3(512), 0, stream,
                       z, sid, eid, kp, b_stat, b_kdiff, w_stat, w_kdiff,
                       KB, W1T, W2T, W3T, b1, b2, b3, W4, b4, out);

    // mechanism-verification probe (own rocprof row)
    hipLaunchKernelGGL(probe_w2F, dim3(256), dim3(512), 0, stream,
                       W2T, b2, sinkW2, 16);
}

// Round 12
// 101.872 us; speedup vs baseline: 1.5834x; 1.5834x over previous
//
#include <hip/hip_runtime.h>
#include <hip/hip_bf16.h>
#include <math.h>

#define STU_NUM   100000
#define PROB_NUM  20000
#define KNOW_NUM  128
#define DIM       128
#define BATCH     8192
#define HIDDEN    512

typedef __attribute__((ext_vector_type(4))) float  f32x4;
typedef __attribute__((ext_vector_type(8))) __bf16 bf16x8;

__device__ __forceinline__ float sigmoidf_(float x) { return 1.0f / (1.0f + __expf(-x)); }
__device__ __forceinline__ float tanh_fast(float x) { return 1.0f - 2.0f / (__expf(2.0f * x) + 1.0f); }

__device__ __forceinline__ int swz(int row, int kk) {
    return row * 128 + ((((kk >> 3) ^ (row & 7)) << 4) | ((kk & 7) << 1));
}
__device__ __forceinline__ bf16x8 rfragK(const char* buf, int row, int kk) {
    return *reinterpret_cast<const bf16x8*>(buf + (kk >> 6) * 4096 + swz(row, kk & 63));
}
__device__ __forceinline__ void wput(char* buf, int row, int col, float v) {
    *reinterpret_cast<__bf16*>(buf + (col >> 6) * 4096 + swz(row, col & 63)) = (__bf16)v;
}
__device__ __forceinline__ f32x4 mfma16(bf16x8 a, bf16x8 b, f32x4 c) {
    return __builtin_amdgcn_mfma_f32_16x16x32_bf16(a, b, c, 0, 0, 0);
}

// Raw inline-asm 16B global load. asm volatile CANNOT be sunk/reordered by the
// scheduler (R10/R11: both plain loads and sched_barrier-fenced loads were
// sunk back to uses, VGPR 60/88, per-k-step latency serialization intact).
// NOTE: result is NOT ready until an explicit s_waitcnt vmcnt -- callers must
// wait before any use (rule #18 pattern: asm waitcnt + sched_barrier(0)).
__device__ __forceinline__ bf16x8 gload16(const __bf16* p) {
    bf16x8 r;
    asm volatile("global_load_dwordx4 %0, %1, off"
                 : "=v"(r) : "v"(p) : "memory");
    return r;
}

// ---------------------------------------------------------------------------
// MLP layer, ASM-FORCED breadth-first weight preload: all NKT*CG slice loads
// issue back-to-back (volatile program order), ONE pipelined drain
// (s_waitcnt vmcnt(0) + sched_barrier), then the MFMA loop runs on registers.
// W2: 32 loads = 128 VGPR live -> needs the 256-VGPR budget of (512,2).
// ---------------------------------------------------------------------------
template<int N, int K>
__device__ __forceinline__ void layerA(const __bf16* __restrict__ WT,
                                       const float* __restrict__ bias,
                                       const char* __restrict__ A, char* __restrict__ O,
                                       int wid, int lane) {
    constexpr int NKT = K / 32;
    constexpr int CG  = N / 128;
    const int l15 = lane & 15, lk = (lane >> 4) * 8;
    const int nb = wid * (N / 8);

    bf16x8 wf[NKT][CG];
    #pragma unroll
    for (int kt = 0; kt < NKT; ++kt)
        #pragma unroll
        for (int c = 0; c < CG; ++c)
            wf[kt][c] = gload16(WT + (size_t)(nb + c * 16 + l15) * K + kt * 32 + lk);
    asm volatile("s_waitcnt vmcnt(0)" ::: "memory");
    __builtin_amdgcn_sched_barrier(0);   // rule #18: nothing crosses the wait

    f32x4 acc[2][CG];
    #pragma unroll
    for (int i = 0; i < 2; ++i)
        #pragma unroll
        for (int c = 0; c < CG; ++c) acc[i][c] = (f32x4){0.f, 0.f, 0.f, 0.f};

    #pragma unroll
    for (int kt = 0; kt < NKT; ++kt) {
        const int kk = kt * 32 + lk;
        bf16x8 a0 = rfragK(A, l15, kk);
        bf16x8 a1 = rfragK(A, 16 + l15, kk);
        #pragma unroll
        for (int c = 0; c < CG; ++c) {
            acc[0][c] = mfma16(a0, wf[kt][c], acc[0][c]);
            acc[1][c] = mfma16(a1, wf[kt][c], acc[1][c]);
        }
    }
    #pragma unroll
    for (int c = 0; c < CG; ++c) {
        const int col = nb + c * 16 + l15;
        const float bv = bias[col];
        #pragma unroll
        for (int i = 0; i < 2; ++i)
            #pragma unroll
            for (int r = 0; r < 4; ++r)
                wput(O, i * 16 + (lane >> 4) * 4 + r, col, tanh_fast(acc[i][c][r] + bv));
    }
}

// ---------------------------------------------------------------------------
// Fused kernel: R4 structure + 256-VGPR budget + ASM breadth preload.
// ---------------------------------------------------------------------------
__global__ __launch_bounds__(512, 2) void fused_kernel(
    const float* __restrict__ z, const int* __restrict__ sid, const int* __restrict__ eid,
    const float* __restrict__ kp, const float* __restrict__ bstat, const float* __restrict__ bkdiff,
    const float* __restrict__ w_stat, const float* __restrict__ w_kdiff,
    const __bf16* __restrict__ KB, const __bf16* __restrict__ W1T,
    const __bf16* __restrict__ W2T, const __bf16* __restrict__ W3T,
    const float* __restrict__ b1, const float* __restrict__ b2, const float* __restrict__ b3,
    const float* __restrict__ W4, const float* __restrict__ b4,
    float* __restrict__ out) {
    __shared__ char lds[81920];
    char* Xs = lds;
    char* Xk = lds + 8192;
    char* st = lds + 16384;
    char* h1 = lds + 24576;
    char* h2 = lds + 57344;
    char* h3 = lds + 73728;

    const int t = threadIdx.x, lane = t & 63, wid = t >> 6;
    const int l15 = lane & 15, lk = (lane >> 4) * 8;
    const int rb0 = blockIdx.x * 32;
    const int colb = wid * 16 + l15;

    {
        int gr = t >> 3, row = gr & 31;
        bool ise = gr >= 32;
        int zrow = ise ? eid[rb0 + row] : sid[rb0 + row];
        const float* w = ise ? w_kdiff : w_stat;
        char* Xb = ise ? Xk : Xs;
        int c0 = (t & 7) * 16;
        const float4* zp = reinterpret_cast<const float4*>(z + (size_t)zrow * DIM + c0);
        const float4* wp = reinterpret_cast<const float4*>(w + c0);
        #pragma unroll
        for (int q = 0; q < 2; ++q) {
            float4 za = zp[2 * q], zb = zp[2 * q + 1];
            float4 wa = wp[2 * q], wb = wp[2 * q + 1];
            bf16x8 o;
            o[0] = (__bf16)(za.x * wa.x);  o[1] = (__bf16)(za.y * wa.y);
            o[2] = (__bf16)(za.z * wa.z);  o[3] = (__bf16)(za.w * wa.w);
            o[4] = (__bf16)(zb.x * wb.x);  o[5] = (__bf16)(zb.y * wb.y);
            o[6] = (__bf16)(zb.z * wb.z);  o[7] = (__bf16)(zb.w * wb.w);
            int c = c0 + q * 8;
            *reinterpret_cast<bf16x8*>(Xb + (c >> 6) * 4096 + swz(row, c & 63)) = o;
        }
    }
    bf16x8 kbf[4];
    #pragma unroll
    for (int kt = 0; kt < 4; ++kt)
        kbf[kt] = *reinterpret_cast<const bf16x8*>(KB + (size_t)colb * DIM + kt * 32 + lk);
    float kpv[2][4];
    #pragma unroll
    for (int i = 0; i < 2; ++i)
        #pragma unroll
        for (int r = 0; r < 4; ++r)
            kpv[i][r] = kp[(size_t)(rb0 + i * 16 + (lane >> 4) * 4 + r) * KNOW_NUM + colb];
    __syncthreads();

    {
        f32x4 aS[2], aK[2];
        #pragma unroll
        for (int i = 0; i < 2; ++i) { aS[i] = (f32x4){0,0,0,0}; aK[i] = (f32x4){0,0,0,0}; }
        #pragma unroll
        for (int kt = 0; kt < 4; ++kt) {
            const int kk = kt * 32 + lk;
            bf16x8 s0 = rfragK(Xs, l15, kk), s1 = rfragK(Xs, 16 + l15, kk);
            bf16x8 q0 = rfragK(Xk, l15, kk), q1 = rfragK(Xk, 16 + l15, kk);
            aS[0] = mfma16(s0, kbf[kt], aS[0]);
            aS[1] = mfma16(s1, kbf[kt], aS[1]);
            aK[0] = mfma16(q0, kbf[kt], aK[0]);
            aK[1] = mfma16(q1, kbf[kt], aK[1]);
        }
        const float bs = bstat[0], bk = bkdiff[0];
        #pragma unroll
        for (int i = 0; i < 2; ++i)
            #pragma unroll
            for (int r = 0; r < 4; ++r) {
                float v = kpv[i][r] * (sigmoidf_(aS[i][r] + bs) - sigmoidf_(aK[i][r] + bk));
                wput(st, i * 16 + (lane >> 4) * 4 + r, colb, v);
            }
    }
    __syncthreads();

    layerA<HIDDEN,     DIM>       (W1T, b1, st, h1, wid, lane);
    __syncthreads();
    layerA<HIDDEN / 2, HIDDEN>    (W2T, b2, h1, h2, wid, lane);
    __syncthreads();
    layerA<HIDDEN / 4, HIDDEN / 2>(W3T, b3, h2, h3, wid, lane);
    __syncthreads();

    {
        int row  = t >> 4;
        int part = (t & 15) * 8;
        bf16x8 h = rfragK(h3, row, part);
        float s = 0.f;
        #pragma unroll
        for (int j = 0; j < 8; ++j) s += (float)h[j] * W4[part + j];
        s += __shfl_xor(s, 1); s += __shfl_xor(s, 2);
        s += __shfl_xor(s, 4); s += __shfl_xor(s, 8);
        if ((t & 15) == 0) out[rb0 + row] = sigmoidf_(s + b4[0]);
    }
}

// ---------------------------------------------------------------------------
// probe_w2A: verifies the ASM-forced preload. Pre-committed reads:
//   VGPR >= 170 AND per-rep <= 2.5us  -> mechanism works, strip probes next.
//   VGPR high, per-rep ~8us           -> L2 request-rate bound, pivot.
//   absmax blown                      -> RA hazard, waitcnt goes inside asm.
// ---------------------------------------------------------------------------
__global__ __launch_bounds__(512, 2) void probe_w2A(
    const __bf16* __restrict__ WT, const float* __restrict__ bias,
    float* __restrict__ sink, int reps) {
    __shared__ char lds[81920];
    const int t = threadIdx.x, lane = t & 63, wid = t >> 6;
    for (int i = t; i < 20480; i += 512) reinterpret_cast<unsigned*>(lds)[i] = 0x3DCC3DCCu;
    __syncthreads();
    #pragma unroll 1
    for (int rep = 0; rep < reps; ++rep) {
        int off = 0; asm volatile("" : "+s"(off));
        layerA<HIDDEN / 2, HIDDEN>(WT + off, bias, (const char*)lds + off, lds + 40960, wid, lane);
        __syncthreads();
    }
    if (t == 0) sink[blockIdx.x] = *reinterpret_cast<float*>(lds + 40960);
}

// ---------------------------------------------------------------------------
// prep: f32 -> bf16 weight reorg, READ-coalesced (unchanged).
// ---------------------------------------------------------------------------
__global__ void prep_kernel(const float* __restrict__ z,
                            const float* __restrict__ W1, const float* __restrict__ W2,
                            const float* __restrict__ W3,
                            __bf16* __restrict__ KB, __bf16* __restrict__ W1T,
                            __bf16* __restrict__ W2T, __bf16* __restrict__ W3T) {
    int i = blockIdx.x * 256 + threadIdx.x;
    if (i < 16384) { KB[i] = (__bf16)z[(size_t)(STU_NUM + PROB_NUM) * DIM + i]; return; }
    i -= 16384;
    if (i < 65536) {
        int k = i >> 9, n = i & 511;
        W1T[(size_t)n * DIM + k] = (__bf16)W1[i]; return;
    }
    i -= 65536;
    if (i < 131072) {
        int k = i >> 8, n = i & 255;
        W2T[(size_t)n * HIDDEN + k] = (__bf16)W2[i]; return;
    }
    i -= 131072;
    if (i < 32768) {
        int k = i >> 7, n = i & 127;
        W3T[(size_t)n * (HIDDEN / 2) + k] = (__bf16)W3[i];
    }
}

extern "C" void kernel_launch(void* const* d_in, const int* in_sizes, int n_in,
                              void* d_out, int out_size, void* d_ws, size_t ws_size,
                              hipStream_t stream) {
    const float* z       = (const float*)d_in[0];
    const int*   sid     = (const int*)d_in[1];
    const int*   eid     = (const int*)d_in[2];
    const float* kp      = (const float*)d_in[3];
    const float* w_stat  = (const float*)d_in[4];
    const float* b_stat  = (const float*)d_in[5];
    const float* w_kdiff = (const float*)d_in[6];
    const float* b_kdiff = (const float*)d_in[7];
    const float* W1      = (const float*)d_in[8];
    const float* b1      = (const float*)d_in[9];
    const float* W2      = (const float*)d_in[10];
    const float* b2      = (const float*)d_in[11];
    const float* W3      = (const float*)d_in[12];
    const float* b3      = (const float*)d_in[13];
    const float* W4      = (const float*)d_in[14];
    const float* b4      = (const float*)d_in[15];
    float* out = (float*)d_out;

    char* ws = (char*)d_ws;
    __bf16* KB  = (__bf16*)(ws + 0);        //  32 KB
    __bf16* W1T = (__bf16*)(ws + 32768);    // 128 KB
    __bf16* W2T = (__bf16*)(ws + 163840);   // 256 KB
    __bf16* W3T = (__bf16*)(ws + 425984);   //  64 KB
    float* sinkW2 = (float*)(ws + (1 << 20));

    hipLaunchKernelGGL(prep_kernel, dim3(960), dim3(256), 0, stream,
                       z, W1, W2, W3, KB, W1T, W2T, W3T);

    hipLaunchKernelGGL(fused_kernel, dim3(BATCH / 32), dim3(512), 0, stream,
                       z, sid, eid, kp, b_stat, b_kdiff, w_stat, w_kdiff,
                       KB, W1T, W2T, W3T, b1, b2, b3, W4, b4, out);

    // mechanism-verification probe (own rocprof row)
    hipLaunchKernelGGL(probe_w2A, dim3(256), dim3(512), 0, stream,
                       W2T, b2, sinkW2, 8);
}